// Round 18
// baseline (292.589 us; speedup 1.0000x reference)
//
#include <hip/hip_runtime.h>
#include <hip/hip_bf16.h>

// CaMLoss fused forward for MI355X (gfx950).
// B=4096, D=2048, C=1024. Assumes D%512==0 (R in {1,2,4}), B%256==0, C%256==0.
// enb/cnb stored SLOT-SWIZZLED: within each 64-elem chunk of row i, 8-elem slot
// s lives at s ^ (i&7); ds_read at col ^ ((row&7)<<3) is conflict-free (verified 0).
// R18 = R17 (best: 143.9us) + k_final fused into k_pd_all via last-block ticket:
//   each pd block: epilogue atomics -> __threadfence (release) -> ticket
//   atomicAdd(done); block with ticket nwg-1 acquire-fences and runs the loss
//   reduction reading stats with agent-scope atomic loads (cross-XCD safe).
//   done zeroed in k_prep each call (graph-replay deterministic). 3 launches.
//   k_pd_all core: R9 retention pipeline (plateau 87.4-87.9us across R3-R12;
//   124 VGPR, no spill) + super-tiled tri map. Unchanged.

typedef __attribute__((ext_vector_type(8))) short short8;
typedef __attribute__((ext_vector_type(4))) float f32x4;

#define BIGF 1e6f
#define EPSC 1e-12f

__device__ __forceinline__ float bf2f(unsigned short u){
  unsigned int x = ((unsigned int)u) << 16;
  return __uint_as_float(x);
}
__device__ __forceinline__ unsigned short f2bf(float f){
  __hip_bfloat16 h = __float2bfloat16(f);
  return *reinterpret_cast<unsigned short*>(&h);
}

// async global->LDS, 16B per lane, wave-uniform LDS base + lane*16
#define GLL16(gptr, lptr) \
  __builtin_amdgcn_global_load_lds( \
      (const __attribute__((address_space(1))) unsigned int*)(gptr), \
      (__attribute__((address_space(3))) unsigned int*)(lptr), 16, 0, 0)

#define VMWAIT(S) asm volatile("s_waitcnt " S ::: "memory")
#define SBAR()    asm volatile("s_barrier" ::: "memory")

// ---------------- prep: stat-init + normalize (row waves) | member-scan + centers (center waves) ----------------
template<int R>   // R = D/512
__global__ __launch_bounds__(256) void k_prep(const float* __restrict__ emb,
    const float* __restrict__ cval, const float* __restrict__ ccnt,
    const int* __restrict__ labels,
    int* __restrict__ cnt, int* __restrict__ members,
    unsigned short* __restrict__ enb, unsigned short* __restrict__ cnb,
    float* __restrict__ exx, float* __restrict__ cxx,
    unsigned* __restrict__ mn0, unsigned* __restrict__ mx0, unsigned* __restrict__ fl0,
    unsigned* __restrict__ mn1, unsigned* __restrict__ mx1, unsigned* __restrict__ fl1,
    unsigned* __restrict__ done,
    int B, int D, int MMAX, int nbNorm){
  __shared__ int memL[4][64];
  int w = threadIdx.x >> 6, lane = threadIdx.x & 63;
  if (blockIdx.x == 0 && threadIdx.x == 0) *done = 0u;   // reset ticket each call
  if ((int)blockIdx.x < nbNorm){
    // ---- row wave: stat init + normalize ----
    int i = blockIdx.x * 4 + w;
    if (lane == 0){
      unsigned bigbits = __float_as_uint(BIGF);
      mn0[i] = bigbits; mx0[i] = 0u; fl0[i] = 0u;
      mn1[i] = bigbits; mx1[i] = 0u; fl1[i] = 0u;
    }
    const float* row = emb + (size_t)i * D;
    float v[R][8];
    float ss = 0.f;
    #pragma unroll
    for (int r = 0; r < R; ++r){
      int base = r * 512 + lane * 8;
      float4 a = *reinterpret_cast<const float4*>(&row[base]);
      float4 b = *reinterpret_cast<const float4*>(&row[base + 4]);
      v[r][0]=a.x; v[r][1]=a.y; v[r][2]=a.z; v[r][3]=a.w;
      v[r][4]=b.x; v[r][5]=b.y; v[r][6]=b.z; v[r][7]=b.w;
      #pragma unroll
      for (int k = 0; k < 8; ++k) ss += v[r][k] * v[r][k];
    }
    #pragma unroll
    for (int s = 1; s < 64; s <<= 1) ss += __shfl_xor(ss, s);
    float inv = 1.f / (sqrtf(ss) + EPSC);
    unsigned short* orow = enb + (size_t)i * D;
    int xr = (i & 7) << 3;
    #pragma unroll
    for (int r = 0; r < R; ++r){
      int base = (r * 512 + lane * 8) ^ xr;
      short8 o;
      #pragma unroll
      for (int k = 0; k < 8; ++k) o[k] = (short)f2bf(v[r][k] * inv);
      *reinterpret_cast<short8*>(&orow[base]) = o;
    }
    if (lane == 0) exx[i] = ss * inv * inv;
  } else {
    // ---- center wave: ballot member scan (ascending index = deterministic) ----
    int c = ((int)blockIdx.x - nbNorm) * 4 + w;
    int n = 0;
    int nit = (B + 63) >> 6;
    for (int itc = 0; itc < nit; ++itc){
      int idx = itc * 64 + lane;
      int lab = (idx < B) ? labels[idx] : -1;
      unsigned long long bm = __ballot(lab == c);
      if (lab == c){
        int rk = n + (int)__popcll(bm & ((1ull << lane) - 1ull));
        if (rk < MMAX) memL[w][rk] = idx;
      }
      n += (int)__popcll(bm);
    }
    int m = n < MMAX ? n : MMAX;
    if (lane < m) members[c * MMAX + lane] = memL[w][lane];   // publish for k_hpos
    if (lane == 0) cnt[c] = n;
    // ---- center: accumulate raw emb member rows + cval/ccnt math ----
    float acc[R][8];
    #pragma unroll
    for (int r = 0; r < R; ++r)
      #pragma unroll
      for (int k = 0; k < 8; ++k) acc[r][k] = 0.f;
    for (int e = 0; e < m; ++e){
      const float* row = emb + (size_t)memL[w][e] * D;
      #pragma unroll
      for (int r = 0; r < R; ++r){
        int base = r * 512 + lane * 8;
        float4 a = *reinterpret_cast<const float4*>(&row[base]);
        float4 b = *reinterpret_cast<const float4*>(&row[base + 4]);
        acc[r][0]+=a.x; acc[r][1]+=a.y; acc[r][2]+=a.z; acc[r][3]+=a.w;
        acc[r][4]+=b.x; acc[r][5]+=b.y; acc[r][6]+=b.z; acc[r][7]+=b.w;
      }
    }
    float cf = (float)n;
    float ss = 0.f;
    #pragma unroll
    for (int r = 0; r < R; ++r){
      int base = r * 512 + lane * 8;
      float4 u0 = *reinterpret_cast<const float4*>(&ccnt[(size_t)c * D + base]);
      float4 u1 = *reinterpret_cast<const float4*>(&ccnt[(size_t)c * D + base + 4]);
      float4 w0 = *reinterpret_cast<const float4*>(&cval[(size_t)c * D + base]);
      float4 w1 = *reinterpret_cast<const float4*>(&cval[(size_t)c * D + base + 4]);
      float uc[8] = {u0.x,u0.y,u0.z,u0.w,u1.x,u1.y,u1.z,u1.w};
      float wv[8] = {w0.x,w0.y,w0.z,w0.w,w1.x,w1.y,w1.z,w1.w};
      #pragma unroll
      for (int k = 0; k < 8; ++k){
        float u = uc[k] + cf;
        float vv = wv[k] + acc[r][k];
        float ce = (u > 0.f) ? (vv / fmaxf(u, 1.f)) : 0.f;
        acc[r][k] = ce; ss += ce * ce;
      }
    }
    #pragma unroll
    for (int s = 1; s < 64; s <<= 1) ss += __shfl_xor(ss, s);
    float inv = 1.f / (sqrtf(ss) + EPSC);
    int xr = (c & 7) << 3;
    #pragma unroll
    for (int r = 0; r < R; ++r){
      int base = (r * 512 + lane * 8) ^ xr;
      short8 o;
      #pragma unroll
      for (int k = 0; k < 8; ++k) o[k] = (short)f2bf(acc[r][k] * inv);
      *reinterpret_cast<short8*>(&cnb[(size_t)c * D + base]) = o;
    }
    if (lane == 0) cxx[c] = ss * inv * inv;
  }
}

// ---------------- hardest positive: one wave per row ----------------
template<int NCH>
__global__ __launch_bounds__(256) void k_hpos(const unsigned short* __restrict__ enb,
    const unsigned short* __restrict__ cnb, const float* __restrict__ exx,
    const float* __restrict__ cxx, const int* __restrict__ labels,
    const int* __restrict__ cnt, const int* __restrict__ members,
    float* __restrict__ hpos, int D, int MMAX){
  int w = threadIdx.x >> 6, lane = threadIdx.x & 63;
  int i = blockIdx.x * 4 + w;
  int li = labels[i];
  const unsigned short* arow = enb + (size_t)i * D;
  int xri = (i & 7) << 3;
  float av[NCH][8];
  #pragma unroll
  for (int ch = 0; ch < NCH; ++ch){
    short8 a8 = *reinterpret_cast<const short8*>(&arow[(ch * 512 + lane * 8) ^ xri]);
    #pragma unroll
    for (int k = 0; k < 8; ++k) av[ch][k] = bf2f((unsigned short)a8[k]);
  }
  float xi = exx[i];
  float hp = 0.f;
  int m = cnt[li] < MMAX ? cnt[li] : MMAX;
  for (int e = 0; e < m; ++e){
    int j = members[li * MMAX + e];
    if (j == i) continue;                     // wave-uniform
    const unsigned short* brow = enb + (size_t)j * D;
    int xrj = (j & 7) << 3;
    float p = 0.f;
    #pragma unroll
    for (int ch = 0; ch < NCH; ++ch){
      short8 b8 = *reinterpret_cast<const short8*>(&brow[(ch * 512 + lane * 8) ^ xrj]);
      #pragma unroll
      for (int k = 0; k < 8; ++k) p += av[ch][k] * bf2f((unsigned short)b8[k]);
    }
    #pragma unroll
    for (int s = 1; s < 64; s <<= 1) p += __shfl_xor(p, s);
    float d2 = xi + exx[j] - 2.f * p;
    hp = fmaxf(hp, sqrtf(fmaxf(d2, EPSC)));
  }
  {
    const unsigned short* brow = cnb + (size_t)li * D;
    int xrc = (li & 7) << 3;
    float p = 0.f;
    #pragma unroll
    for (int ch = 0; ch < NCH; ++ch){
      short8 b8 = *reinterpret_cast<const short8*>(&brow[(ch * 512 + lane * 8) ^ xrc]);
      #pragma unroll
      for (int k = 0; k < 8; ++k) p += av[ch][k] * bf2f((unsigned short)b8[k]);
    }
    #pragma unroll
    for (int s = 1; s < 64; s <<= 1) p += __shfl_xor(p, s);
    float d2 = xi + cxx[li] - 2.f * p;
    hp = fmaxf(hp, sqrtf(fmaxf(d2, EPSC)));
  }
  if (lane == 0) hpos[i] = hp;
}

// ---------------- merged distance pass + fused final reduction ----------------
#define PD_STAGE(SB, KIND, KT) do { \
    unsigned short* dst_ = (SB) + (KIND) * 8192 + wid * (16 * 64); \
    const unsigned short* src_ = ((KIND) < 2 \
        ? gA + (size_t)((KIND) * 128) * D \
        : gB + (size_t)(((KIND) - 2) * 128) * D) + (KT); \
    GLL16(src_, dst_); \
    GLL16(src_ + (size_t)8 * D, dst_ + 8 * 64); \
  } while (0)

#define RD_A(DST, HP) do { \
    _Pragma("unroll") \
    for (int m_ = 0; m_ < 4; ++m_){ \
      DST[m_][0] = *reinterpret_cast<const short8*>(&(HP)[aoff[m_][0]]); \
      DST[m_][1] = *reinterpret_cast<const short8*>(&(HP)[aoff[m_][1]]); \
    } } while (0)

#define RD_B(HP) do { \
    _Pragma("unroll") \
    for (int n_ = 0; n_ < 2; ++n_){ \
      b[n_][0] = *reinterpret_cast<const short8*>(&(HP)[boff[n_][0]]); \
      b[n_][1] = *reinterpret_cast<const short8*>(&(HP)[boff[n_][1]]); \
    } } while (0)

#define LGKM0() do { VMWAIT("lgkmcnt(0)"); __builtin_amdgcn_sched_barrier(0); } while (0)

#define MFMA16(AV, MH, NH) do { \
    __builtin_amdgcn_s_setprio(1); \
    _Pragma("unroll") \
    for (int m_ = 0; m_ < 4; ++m_) \
      _Pragma("unroll") \
      for (int n_ = 0; n_ < 2; ++n_) \
        _Pragma("unroll") \
        for (int ks_ = 0; ks_ < 2; ++ks_) \
          acc[MH][NH][m_][n_] = __builtin_amdgcn_mfma_f32_16x16x32_bf16( \
              AV[m_][ks_], b[n_][ks_], acc[MH][NH][m_][n_], 0, 0, 0); \
    __builtin_amdgcn_s_setprio(0); } while (0)

__global__ __launch_bounds__(512, 2) void k_pd_all(
    const unsigned short* __restrict__ enb,
    const unsigned short* __restrict__ cnb,
    const float* __restrict__ exx, const float* __restrict__ cxx,
    const int* __restrict__ labels, const float* __restrict__ hpos,
    unsigned* __restrict__ mn0, unsigned* __restrict__ mx0, unsigned* __restrict__ fl0,
    unsigned* __restrict__ mn1, unsigned* __restrict__ mx1, unsigned* __restrict__ fl1,
    const float* __restrict__ margin, float* __restrict__ out,
    unsigned* __restrict__ done,
    int B, int D, int nTri, int nby, int nCx)
{
  extern __shared__ unsigned short sm[];           // 2 dbuf x 4 half-slots x 16KB = 128KB
  __shared__ unsigned tickS;
  __shared__ float redF[8];
  // bijective XCD swizzle (m204)
  const int nwg = gridDim.x;
  const int orig = blockIdx.x;
  const int q8 = nwg >> 3, r8 = nwg & 7;
  const int xcd = orig & 7, idx = orig >> 3;
  const int t = (xcd < r8 ? xcd * (q8 + 1) : r8 * (q8 + 1) + (xcd - r8) * q8) + idx;

  const bool pdc = (t >= nTri);
  int bx, by;
  if (!pdc){
    if ((nby & 3) == 0){                           // 4x4 super-cell enumeration
      int gb = 0, cb = 0, rem = t;
      for (;;){
        int sz = (cb < gb) ? 16 : 10;
        if (rem < sz) break;
        rem -= sz;
        if (++cb > gb){ cb = 0; ++gb; }
      }
      if (cb < gb){
        by = gb * 4 + (rem >> 2);
        bx = cb * 4 + (rem & 3);
      } else {
        int r = 0;
        while (((r + 1) * (r + 2)) / 2 <= rem) ++r;
        by = gb * 4 + r;
        bx = cb * 4 + (rem - (r * (r + 1)) / 2);
      }
    } else {
      int b_ = (int)((sqrtf(8.f * (float)t + 1.f) - 1.f) * 0.5f);
      while ((b_ + 1) * (b_ + 2) / 2 <= t) ++b_;
      while (b_ * (b_ + 1) / 2 > t) --b_;
      by = b_; bx = t - b_ * (b_ + 1) / 2;         // bx <= by
    }
  } else {
    int u = t - nTri;
    by = u / nCx; bx = u - by * nCx;
  }
  const unsigned short* cmat = pdc ? cnb : enb;
  const float* cxv = pdc ? cxx : exx;
  unsigned* mnv = pdc ? mn1 : mn0;
  unsigned* mxv = pdc ? mx1 : mx0;
  unsigned* flv = pdc ? fl1 : fl0;

  const int j0 = bx * 256, i0 = by * 256;
  const int tid = threadIdx.x;
  const int wid = tid >> 6, lane = tid & 63;
  const int wr = wid >> 2, wc = wid & 3;           // 2M x 4N wave bands
  const int lr = lane & 15, lg = lane >> 4;

  const int srow = wid * 16 + (lane >> 3);
  const int scol = (lane & 7) * 8;
  const unsigned short* gA = enb  + (size_t)(i0 + srow) * D + scol;
  const unsigned short* gB = cmat + (size_t)(j0 + srow) * D + scol;

  int aoff[4][2], boff[2][2];
  #pragma unroll
  for (int m = 0; m < 4; ++m){
    int ra = wr * 64 + m * 16 + lr;
    #pragma unroll
    for (int ks = 0; ks < 2; ++ks)
      aoff[m][ks] = ra * 64 + ((ks * 32 + lg * 8) ^ ((ra & 7) << 3));
  }
  #pragma unroll
  for (int n = 0; n < 2; ++n){
    int rb = wc * 32 + n * 16 + lr;
    #pragma unroll
    for (int ks = 0; ks < 2; ++ks)
      boff[n][ks] = rb * 64 + ((ks * 32 + lg * 8) ^ ((rb & 7) << 3));
  }

  f32x4 acc[2][2][4][2];
  #pragma unroll
  for (int mh = 0; mh < 2; ++mh)
    #pragma unroll
    for (int nh = 0; nh < 2; ++nh)
      #pragma unroll
      for (int m = 0; m < 4; ++m)
        #pragma unroll
        for (int n = 0; n < 2; ++n)
          acc[mh][nh][m][n] = (f32x4){0.f, 0.f, 0.f, 0.f};

  short8 a0[4][2], a1[4][2], b[2][2];

  const int nt = D >> 6;
  PD_STAGE(sm, 0, 0); PD_STAGE(sm, 1, 0); PD_STAGE(sm, 2, 0); PD_STAGE(sm, 3, 0);
  VMWAIT("vmcnt(0)");
  SBAR();

  for (int it = 0; it < nt; ++it){
    const unsigned short* db = sm + (size_t)(it & 1) * 32768;
    unsigned short* sb = sm + (size_t)((it & 1) ^ 1) * 32768;
    const bool hn = (it + 1 < nt);
    const int ktn = (it + 1) << 6;
    // phase 0: consume (A0,B0); stage A0'
    RD_A(a0, db);
    RD_B(db + 2 * 8192);
    if (hn){ PD_STAGE(sb, 0, ktn); VMWAIT("vmcnt(4)"); } else { VMWAIT("vmcnt(4)"); }
    SBAR();
    LGKM0();
    MFMA16(a0, 0, 0);
    // phase 1: consume (A1,B0); stage B0'
    RD_A(a1, db + 8192);
    if (hn){ PD_STAGE(sb, 2, ktn); VMWAIT("vmcnt(4)"); } else { VMWAIT("vmcnt(2)"); }
    SBAR();
    LGKM0();
    MFMA16(a1, 1, 0);
    // phase 2: consume (A1,B1); stage A1'
    RD_B(db + 3 * 8192);
    if (hn){ PD_STAGE(sb, 1, ktn); VMWAIT("vmcnt(4)"); } else { VMWAIT("vmcnt(0)"); }
    SBAR();
    LGKM0();
    MFMA16(a1, 1, 1);
    // phase 3: consume (A0,B1) from registers; stage B1'
    if (hn){ PD_STAGE(sb, 3, ktn); VMWAIT("vmcnt(4)"); }
    SBAR();
    MFMA16(a0, 0, 1);
  }

  // epilogue
  const bool docol = (!pdc) && (bx != by);
  int jl[2][2]; float xj[2][2], hpj[2][2];
  #pragma unroll
  for (int nh = 0; nh < 2; ++nh)
    #pragma unroll
    for (int n = 0; n < 2; ++n){
      int j = j0 + nh * 128 + wc * 32 + n * 16 + lr;
      jl[nh][n] = pdc ? j : labels[j];
      xj[nh][n] = cxv[j];
      hpj[nh][n] = docol ? hpos[j] : 0.f;
    }
  float cmn[2][2], cmx[2][2]; int cfl[2][2];
  #pragma unroll
  for (int nh = 0; nh < 2; ++nh)
    #pragma unroll
    for (int n = 0; n < 2; ++n){ cmn[nh][n] = BIGF; cmx[nh][n] = 0.f; cfl[nh][n] = 0; }

  #pragma unroll
  for (int mh = 0; mh < 2; ++mh)
    #pragma unroll
    for (int m = 0; m < 4; ++m)
      #pragma unroll
      for (int r = 0; r < 4; ++r){
        int i = i0 + mh * 128 + wr * 64 + m * 16 + lg * 4 + r;
        int li = labels[i];
        float xi = exx[i];
        float hpi = hpos[i];
        float mn = BIGF, mx = 0.f; int fl = 0;
        #pragma unroll
        for (int nh = 0; nh < 2; ++nh)
          #pragma unroll
          for (int n = 0; n < 2; ++n){
            float d2 = xi + xj[nh][n] - 2.f * acc[mh][nh][m][n][r];
            float d  = sqrtf(fmaxf(d2, EPSC));
            bool an = (li != jl[nh][n]);
            bool g  = an && (d > hpi);
            mn = fminf(mn, g ? d : BIGF);
            mx = fmaxf(mx, an ? d : 0.f);
            fl |= (g ? 1 : 0) | (an ? 2 : 0);
            if (docol){
              bool gc = an && (d > hpj[nh][n]);
              cmn[nh][n] = fminf(cmn[nh][n], gc ? d : BIGF);
              cmx[nh][n] = fmaxf(cmx[nh][n], an ? d : 0.f);
              cfl[nh][n] |= (gc ? 1 : 0) | (an ? 2 : 0);
            }
          }
        #pragma unroll
        for (int s = 1; s < 16; s <<= 1){
          mn = fminf(mn, __shfl_xor(mn, s));
          mx = fmaxf(mx, __shfl_xor(mx, s));
          fl |= __shfl_xor(fl, s);
        }
        if (lr == 0){
          atomicMin(&mnv[i], __float_as_uint(mn));
          atomicMax(&mxv[i], __float_as_uint(mx));
          if (fl) atomicOr(&flv[i], (unsigned)fl);
        }
      }
  if (docol){
    #pragma unroll
    for (int nh = 0; nh < 2; ++nh)
      #pragma unroll
      for (int n = 0; n < 2; ++n){
        float mn = cmn[nh][n], mx = cmx[nh][n]; int fl = cfl[nh][n];
        #pragma unroll
        for (int s = 16; s < 64; s <<= 1){
          mn = fminf(mn, __shfl_xor(mn, s));
          mx = fmaxf(mx, __shfl_xor(mx, s));
          fl |= __shfl_xor(fl, s);
        }
        if (lg == 0){
          int j = j0 + nh * 128 + wc * 32 + n * 16 + lr;
          atomicMin(&mn0[j], __float_as_uint(mn));
          atomicMax(&mx0[j], __float_as_uint(mx));
          if (fl) atomicOr(&fl0[j], (unsigned)fl);
        }
      }
  }

  // ---- last-block fused final reduction ----
  __threadfence();                                 // release our atomics
  if (tid == 0) tickS = atomicAdd(done, 1u);
  __syncthreads();
  if (tickS == (unsigned)(nwg - 1)){
    __threadfence();                               // acquire all blocks' atomics
    float part = 0.f;
    float mar = margin[0];
    for (int i = tid; i < B; i += 512){
      unsigned umn0 = __hip_atomic_load(&mn0[i], __ATOMIC_RELAXED, __HIP_MEMORY_SCOPE_AGENT);
      unsigned umn1 = __hip_atomic_load(&mn1[i], __ATOMIC_RELAXED, __HIP_MEMORY_SCOPE_AGENT);
      unsigned umx0 = __hip_atomic_load(&mx0[i], __ATOMIC_RELAXED, __HIP_MEMORY_SCOPE_AGENT);
      unsigned umx1 = __hip_atomic_load(&mx1[i], __ATOMIC_RELAXED, __HIP_MEMORY_SCOPE_AGENT);
      unsigned f0   = __hip_atomic_load(&fl0[i], __ATOMIC_RELAXED, __HIP_MEMORY_SCOPE_AGENT);
      unsigned f1   = __hip_atomic_load(&fl1[i], __ATOMIC_RELAXED, __HIP_MEMORY_SCOPE_AGENT);
      float h_out = fminf(__uint_as_float(umn0), __uint_as_float(umn1));
      float ni  = (!(f0 & 1u)) ? __uint_as_float(umx0) : ((f0 & 2u) ? BIGF : 0.f);
      float nic = (!(f1 & 1u)) ? __uint_as_float(umx1) : ((f1 & 2u) ? BIGF : 0.f);
      float h_in = fmaxf(ni, nic);
      float hneg = fminf(h_out, h_in);
      float tv = hpos[i] - hneg + mar;
      part += fmaxf(tv, 0.f);
    }
    #pragma unroll
    for (int s = 32; s; s >>= 1) part += __shfl_xor(part, s);
    if ((tid & 63) == 0) redF[tid >> 6] = part;
    __syncthreads();
    if (tid == 0){
      float tot = 0.f;
      #pragma unroll
      for (int k = 0; k < 8; ++k) tot += redF[k];
      out[0] = tot / (float)B;
    }
  }
}

extern "C" void kernel_launch(void* const* d_in, const int* in_sizes, int n_in,
                              void* d_out, int out_size, void* d_ws, size_t ws_size,
                              hipStream_t stream){
  const float* emb    = (const float*)d_in[0];
  const int*   labels = (const int*)d_in[1];
  const float* cval   = (const float*)d_in[2];
  const float* ccnt   = (const float*)d_in[3];
  const float* margin = (const float*)d_in[4];
  float* out = (float*)d_out;

  int B = in_sizes[1];
  int D = in_sizes[0] / B;
  int C = in_sizes[2] / D;
  const int MMAX = 64;

  char* ws = (char*)d_ws;
  size_t off = 0;
  auto alloc = [&](size_t bytes)->char*{
    char* p = ws + off;
    off = (off + bytes + 255) & ~(size_t)255;
    return p;
  };
  unsigned short* enb = (unsigned short*)alloc((size_t)B * D * 2);
  unsigned short* cnb = (unsigned short*)alloc((size_t)C * D * 2);
  float* exx  = (float*)alloc((size_t)B * 4);
  float* cxx  = (float*)alloc((size_t)C * 4);
  float* hpos = (float*)alloc((size_t)B * 4);
  unsigned* mn0 = (unsigned*)alloc((size_t)B * 4);
  unsigned* mx0 = (unsigned*)alloc((size_t)B * 4);
  unsigned* fl0 = (unsigned*)alloc((size_t)B * 4);
  unsigned* mn1 = (unsigned*)alloc((size_t)B * 4);
  unsigned* mx1 = (unsigned*)alloc((size_t)B * 4);
  unsigned* fl1 = (unsigned*)alloc((size_t)B * 4);
  int* cnt     = (int*)alloc((size_t)C * 4);
  int* members = (int*)alloc((size_t)C * MMAX * 4);
  unsigned* done = (unsigned*)alloc(256);
  (void)ws_size; (void)n_in; (void)out_size;

  hipFuncSetAttribute((const void*)k_pd_all,
                      hipFuncAttributeMaxDynamicSharedMemorySize, 131072);

  int nbNorm = B / 4, nbCent = C / 4;
  int R = D >> 9;
  if (R == 4){
    k_prep<4><<<nbNorm + nbCent, 256, 0, stream>>>(emb, cval, ccnt, labels, cnt, members,
                                                   enb, cnb, exx, cxx,
                                                   mn0, mx0, fl0, mn1, mx1, fl1, done,
                                                   B, D, MMAX, nbNorm);
  } else if (R == 2){
    k_prep<2><<<nbNorm + nbCent, 256, 0, stream>>>(emb, cval, ccnt, labels, cnt, members,
                                                   enb, cnb, exx, cxx,
                                                   mn0, mx0, fl0, mn1, mx1, fl1, done,
                                                   B, D, MMAX, nbNorm);
  } else {
    k_prep<1><<<nbNorm + nbCent, 256, 0, stream>>>(emb, cval, ccnt, labels, cnt, members,
                                                   enb, cnb, exx, cxx,
                                                   mn0, mx0, fl0, mn1, mx1, fl1, done,
                                                   B, D, MMAX, nbNorm);
  }

  switch (R){
    case 1: k_hpos<1><<<B/4, 256, 0, stream>>>(enb, cnb, exx, cxx, labels, cnt, members, hpos, D, MMAX); break;
    case 2: k_hpos<2><<<B/4, 256, 0, stream>>>(enb, cnb, exx, cxx, labels, cnt, members, hpos, D, MMAX); break;
    default: k_hpos<4><<<B/4, 256, 0, stream>>>(enb, cnb, exx, cxx, labels, cnt, members, hpos, D, MMAX); break;
  }

  int nby = B / 256, nCx = C / 256;
  int nTri = nby * (nby + 1) / 2;
  k_pd_all<<<nTri + nby * nCx, 512, 131072, stream>>>(
      enb, cnb, exx, cxx, labels, hpos,
      mn0, mx0, fl0, mn1, mx1, fl1, margin, out, done,
      B, D, nTri, nby, nCx);
}

// Round 19
// 143.716 us; speedup vs baseline: 2.0359x; 2.0359x over previous
//
#include <hip/hip_runtime.h>
#include <hip/hip_bf16.h>

// CaMLoss fused forward for MI355X (gfx950).
// B=4096, D=2048, C=1024. Assumes D%512==0 (R in {1,2,4}), B%256==0, C%256==0.
// enb/cnb stored SLOT-SWIZZLED: within each 64-elem chunk of row i, 8-elem slot
// s lives at s ^ (i&7); ds_read at col ^ ((row&7)<<3) is conflict-free (verified 0).
// R19 = exact revert to R17 (best measured: 143.9us, 4 launches):
//   k_prep (stat-init + norm row waves | member-scan + centers center waves),
//   k_hpos per-row, k_pd_all = R9 retention pipeline (plateau 87.4-88.2us
//   across R3-R12 schedule variants; 124 VGPR, no spill) + super-tiled tri map,
//   k_final 1024 threads SEPARATE.
//   R18's last-block fusion REVERTED: its static __shared__ (tickS/redF) on top
//   of 128KB dynamic LDS dropped occupancy to 1 block/CU -> pd pass 241us.

typedef __attribute__((ext_vector_type(8))) short short8;
typedef __attribute__((ext_vector_type(4))) float f32x4;

#define BIGF 1e6f
#define EPSC 1e-12f

__device__ __forceinline__ float bf2f(unsigned short u){
  unsigned int x = ((unsigned int)u) << 16;
  return __uint_as_float(x);
}
__device__ __forceinline__ unsigned short f2bf(float f){
  __hip_bfloat16 h = __float2bfloat16(f);
  return *reinterpret_cast<unsigned short*>(&h);
}

// async global->LDS, 16B per lane, wave-uniform LDS base + lane*16
#define GLL16(gptr, lptr) \
  __builtin_amdgcn_global_load_lds( \
      (const __attribute__((address_space(1))) unsigned int*)(gptr), \
      (__attribute__((address_space(3))) unsigned int*)(lptr), 16, 0, 0)

#define VMWAIT(S) asm volatile("s_waitcnt " S ::: "memory")
#define SBAR()    asm volatile("s_barrier" ::: "memory")

// ---------------- prep: stat-init + normalize (row waves) | member-scan + centers (center waves) ----------------
template<int R>   // R = D/512
__global__ __launch_bounds__(256) void k_prep(const float* __restrict__ emb,
    const float* __restrict__ cval, const float* __restrict__ ccnt,
    const int* __restrict__ labels,
    int* __restrict__ cnt, int* __restrict__ members,
    unsigned short* __restrict__ enb, unsigned short* __restrict__ cnb,
    float* __restrict__ exx, float* __restrict__ cxx,
    unsigned* __restrict__ mn0, unsigned* __restrict__ mx0, unsigned* __restrict__ fl0,
    unsigned* __restrict__ mn1, unsigned* __restrict__ mx1, unsigned* __restrict__ fl1,
    int B, int D, int MMAX, int nbNorm){
  __shared__ int memL[4][64];
  int w = threadIdx.x >> 6, lane = threadIdx.x & 63;
  if ((int)blockIdx.x < nbNorm){
    // ---- row wave: stat init + normalize ----
    int i = blockIdx.x * 4 + w;
    if (lane == 0){
      unsigned bigbits = __float_as_uint(BIGF);
      mn0[i] = bigbits; mx0[i] = 0u; fl0[i] = 0u;
      mn1[i] = bigbits; mx1[i] = 0u; fl1[i] = 0u;
    }
    const float* row = emb + (size_t)i * D;
    float v[R][8];
    float ss = 0.f;
    #pragma unroll
    for (int r = 0; r < R; ++r){
      int base = r * 512 + lane * 8;
      float4 a = *reinterpret_cast<const float4*>(&row[base]);
      float4 b = *reinterpret_cast<const float4*>(&row[base + 4]);
      v[r][0]=a.x; v[r][1]=a.y; v[r][2]=a.z; v[r][3]=a.w;
      v[r][4]=b.x; v[r][5]=b.y; v[r][6]=b.z; v[r][7]=b.w;
      #pragma unroll
      for (int k = 0; k < 8; ++k) ss += v[r][k] * v[r][k];
    }
    #pragma unroll
    for (int s = 1; s < 64; s <<= 1) ss += __shfl_xor(ss, s);
    float inv = 1.f / (sqrtf(ss) + EPSC);
    unsigned short* orow = enb + (size_t)i * D;
    int xr = (i & 7) << 3;
    #pragma unroll
    for (int r = 0; r < R; ++r){
      int base = (r * 512 + lane * 8) ^ xr;
      short8 o;
      #pragma unroll
      for (int k = 0; k < 8; ++k) o[k] = (short)f2bf(v[r][k] * inv);
      *reinterpret_cast<short8*>(&orow[base]) = o;
    }
    if (lane == 0) exx[i] = ss * inv * inv;
  } else {
    // ---- center wave: ballot member scan (ascending index = deterministic) ----
    int c = ((int)blockIdx.x - nbNorm) * 4 + w;
    int n = 0;
    int nit = (B + 63) >> 6;
    for (int itc = 0; itc < nit; ++itc){
      int idx = itc * 64 + lane;
      int lab = (idx < B) ? labels[idx] : -1;
      unsigned long long bm = __ballot(lab == c);
      if (lab == c){
        int rk = n + (int)__popcll(bm & ((1ull << lane) - 1ull));
        if (rk < MMAX) memL[w][rk] = idx;
      }
      n += (int)__popcll(bm);
    }
    int m = n < MMAX ? n : MMAX;
    if (lane < m) members[c * MMAX + lane] = memL[w][lane];   // publish for k_hpos
    if (lane == 0) cnt[c] = n;
    // ---- center: accumulate raw emb member rows + cval/ccnt math ----
    float acc[R][8];
    #pragma unroll
    for (int r = 0; r < R; ++r)
      #pragma unroll
      for (int k = 0; k < 8; ++k) acc[r][k] = 0.f;
    for (int e = 0; e < m; ++e){
      const float* row = emb + (size_t)memL[w][e] * D;
      #pragma unroll
      for (int r = 0; r < R; ++r){
        int base = r * 512 + lane * 8;
        float4 a = *reinterpret_cast<const float4*>(&row[base]);
        float4 b = *reinterpret_cast<const float4*>(&row[base + 4]);
        acc[r][0]+=a.x; acc[r][1]+=a.y; acc[r][2]+=a.z; acc[r][3]+=a.w;
        acc[r][4]+=b.x; acc[r][5]+=b.y; acc[r][6]+=b.z; acc[r][7]+=b.w;
      }
    }
    float cf = (float)n;
    float ss = 0.f;
    #pragma unroll
    for (int r = 0; r < R; ++r){
      int base = r * 512 + lane * 8;
      float4 u0 = *reinterpret_cast<const float4*>(&ccnt[(size_t)c * D + base]);
      float4 u1 = *reinterpret_cast<const float4*>(&ccnt[(size_t)c * D + base + 4]);
      float4 w0 = *reinterpret_cast<const float4*>(&cval[(size_t)c * D + base]);
      float4 w1 = *reinterpret_cast<const float4*>(&cval[(size_t)c * D + base + 4]);
      float uc[8] = {u0.x,u0.y,u0.z,u0.w,u1.x,u1.y,u1.z,u1.w};
      float wv[8] = {w0.x,w0.y,w0.z,w0.w,w1.x,w1.y,w1.z,w1.w};
      #pragma unroll
      for (int k = 0; k < 8; ++k){
        float u = uc[k] + cf;
        float vv = wv[k] + acc[r][k];
        float ce = (u > 0.f) ? (vv / fmaxf(u, 1.f)) : 0.f;
        acc[r][k] = ce; ss += ce * ce;
      }
    }
    #pragma unroll
    for (int s = 1; s < 64; s <<= 1) ss += __shfl_xor(ss, s);
    float inv = 1.f / (sqrtf(ss) + EPSC);
    int xr = (c & 7) << 3;
    #pragma unroll
    for (int r = 0; r < R; ++r){
      int base = (r * 512 + lane * 8) ^ xr;
      short8 o;
      #pragma unroll
      for (int k = 0; k < 8; ++k) o[k] = (short)f2bf(acc[r][k] * inv);
      *reinterpret_cast<short8*>(&cnb[(size_t)c * D + base]) = o;
    }
    if (lane == 0) cxx[c] = ss * inv * inv;
  }
}

// ---------------- hardest positive: one wave per row ----------------
template<int NCH>
__global__ __launch_bounds__(256) void k_hpos(const unsigned short* __restrict__ enb,
    const unsigned short* __restrict__ cnb, const float* __restrict__ exx,
    const float* __restrict__ cxx, const int* __restrict__ labels,
    const int* __restrict__ cnt, const int* __restrict__ members,
    float* __restrict__ hpos, int D, int MMAX){
  int w = threadIdx.x >> 6, lane = threadIdx.x & 63;
  int i = blockIdx.x * 4 + w;
  int li = labels[i];
  const unsigned short* arow = enb + (size_t)i * D;
  int xri = (i & 7) << 3;
  float av[NCH][8];
  #pragma unroll
  for (int ch = 0; ch < NCH; ++ch){
    short8 a8 = *reinterpret_cast<const short8*>(&arow[(ch * 512 + lane * 8) ^ xri]);
    #pragma unroll
    for (int k = 0; k < 8; ++k) av[ch][k] = bf2f((unsigned short)a8[k]);
  }
  float xi = exx[i];
  float hp = 0.f;
  int m = cnt[li] < MMAX ? cnt[li] : MMAX;
  for (int e = 0; e < m; ++e){
    int j = members[li * MMAX + e];
    if (j == i) continue;                     // wave-uniform
    const unsigned short* brow = enb + (size_t)j * D;
    int xrj = (j & 7) << 3;
    float p = 0.f;
    #pragma unroll
    for (int ch = 0; ch < NCH; ++ch){
      short8 b8 = *reinterpret_cast<const short8*>(&brow[(ch * 512 + lane * 8) ^ xrj]);
      #pragma unroll
      for (int k = 0; k < 8; ++k) p += av[ch][k] * bf2f((unsigned short)b8[k]);
    }
    #pragma unroll
    for (int s = 1; s < 64; s <<= 1) p += __shfl_xor(p, s);
    float d2 = xi + exx[j] - 2.f * p;
    hp = fmaxf(hp, sqrtf(fmaxf(d2, EPSC)));
  }
  {
    const unsigned short* brow = cnb + (size_t)li * D;
    int xrc = (li & 7) << 3;
    float p = 0.f;
    #pragma unroll
    for (int ch = 0; ch < NCH; ++ch){
      short8 b8 = *reinterpret_cast<const short8*>(&brow[(ch * 512 + lane * 8) ^ xrc]);
      #pragma unroll
      for (int k = 0; k < 8; ++k) p += av[ch][k] * bf2f((unsigned short)b8[k]);
    }
    #pragma unroll
    for (int s = 1; s < 64; s <<= 1) p += __shfl_xor(p, s);
    float d2 = xi + cxx[li] - 2.f * p;
    hp = fmaxf(hp, sqrtf(fmaxf(d2, EPSC)));
  }
  if (lane == 0) hpos[i] = hp;
}

// ---------------- merged distance pass: R9 retention pipeline + supertiled map ----------------
#define PD_STAGE(SB, KIND, KT) do { \
    unsigned short* dst_ = (SB) + (KIND) * 8192 + wid * (16 * 64); \
    const unsigned short* src_ = ((KIND) < 2 \
        ? gA + (size_t)((KIND) * 128) * D \
        : gB + (size_t)(((KIND) - 2) * 128) * D) + (KT); \
    GLL16(src_, dst_); \
    GLL16(src_ + (size_t)8 * D, dst_ + 8 * 64); \
  } while (0)

#define RD_A(DST, HP) do { \
    _Pragma("unroll") \
    for (int m_ = 0; m_ < 4; ++m_){ \
      DST[m_][0] = *reinterpret_cast<const short8*>(&(HP)[aoff[m_][0]]); \
      DST[m_][1] = *reinterpret_cast<const short8*>(&(HP)[aoff[m_][1]]); \
    } } while (0)

#define RD_B(HP) do { \
    _Pragma("unroll") \
    for (int n_ = 0; n_ < 2; ++n_){ \
      b[n_][0] = *reinterpret_cast<const short8*>(&(HP)[boff[n_][0]]); \
      b[n_][1] = *reinterpret_cast<const short8*>(&(HP)[boff[n_][1]]); \
    } } while (0)

#define LGKM0() do { VMWAIT("lgkmcnt(0)"); __builtin_amdgcn_sched_barrier(0); } while (0)

#define MFMA16(AV, MH, NH) do { \
    __builtin_amdgcn_s_setprio(1); \
    _Pragma("unroll") \
    for (int m_ = 0; m_ < 4; ++m_) \
      _Pragma("unroll") \
      for (int n_ = 0; n_ < 2; ++n_) \
        _Pragma("unroll") \
        for (int ks_ = 0; ks_ < 2; ++ks_) \
          acc[MH][NH][m_][n_] = __builtin_amdgcn_mfma_f32_16x16x32_bf16( \
              AV[m_][ks_], b[n_][ks_], acc[MH][NH][m_][n_], 0, 0, 0); \
    __builtin_amdgcn_s_setprio(0); } while (0)

__global__ __launch_bounds__(512, 2) void k_pd_all(
    const unsigned short* __restrict__ enb,
    const unsigned short* __restrict__ cnb,
    const float* __restrict__ exx, const float* __restrict__ cxx,
    const int* __restrict__ labels, const float* __restrict__ hpos,
    unsigned* __restrict__ mn0, unsigned* __restrict__ mx0, unsigned* __restrict__ fl0,
    unsigned* __restrict__ mn1, unsigned* __restrict__ mx1, unsigned* __restrict__ fl1,
    int D, int nTri, int nby, int nCx)
{
  extern __shared__ unsigned short sm[];           // 2 dbuf x 4 half-slots x 16KB = 128KB
  // bijective XCD swizzle (m204)
  const int nwg = gridDim.x;
  const int orig = blockIdx.x;
  const int q8 = nwg >> 3, r8 = nwg & 7;
  const int xcd = orig & 7, idx = orig >> 3;
  const int t = (xcd < r8 ? xcd * (q8 + 1) : r8 * (q8 + 1) + (xcd - r8) * q8) + idx;

  const bool pdc = (t >= nTri);
  int bx, by;
  if (!pdc){
    if ((nby & 3) == 0){                           // 4x4 super-cell enumeration
      int gb = 0, cb = 0, rem = t;
      for (;;){
        int sz = (cb < gb) ? 16 : 10;
        if (rem < sz) break;
        rem -= sz;
        if (++cb > gb){ cb = 0; ++gb; }
      }
      if (cb < gb){
        by = gb * 4 + (rem >> 2);
        bx = cb * 4 + (rem & 3);
      } else {
        int r = 0;
        while (((r + 1) * (r + 2)) / 2 <= rem) ++r;
        by = gb * 4 + r;
        bx = cb * 4 + (rem - (r * (r + 1)) / 2);
      }
    } else {
      int b_ = (int)((sqrtf(8.f * (float)t + 1.f) - 1.f) * 0.5f);
      while ((b_ + 1) * (b_ + 2) / 2 <= t) ++b_;
      while (b_ * (b_ + 1) / 2 > t) --b_;
      by = b_; bx = t - b_ * (b_ + 1) / 2;         // bx <= by
    }
  } else {
    int u = t - nTri;
    by = u / nCx; bx = u - by * nCx;
  }
  const unsigned short* cmat = pdc ? cnb : enb;
  const float* cxv = pdc ? cxx : exx;
  unsigned* mnv = pdc ? mn1 : mn0;
  unsigned* mxv = pdc ? mx1 : mx0;
  unsigned* flv = pdc ? fl1 : fl0;

  const int j0 = bx * 256, i0 = by * 256;
  const int tid = threadIdx.x;
  const int wid = tid >> 6, lane = tid & 63;
  const int wr = wid >> 2, wc = wid & 3;           // 2M x 4N wave bands
  const int lr = lane & 15, lg = lane >> 4;

  const int srow = wid * 16 + (lane >> 3);
  const int scol = (lane & 7) * 8;
  const unsigned short* gA = enb  + (size_t)(i0 + srow) * D + scol;
  const unsigned short* gB = cmat + (size_t)(j0 + srow) * D + scol;

  int aoff[4][2], boff[2][2];
  #pragma unroll
  for (int m = 0; m < 4; ++m){
    int ra = wr * 64 + m * 16 + lr;
    #pragma unroll
    for (int ks = 0; ks < 2; ++ks)
      aoff[m][ks] = ra * 64 + ((ks * 32 + lg * 8) ^ ((ra & 7) << 3));
  }
  #pragma unroll
  for (int n = 0; n < 2; ++n){
    int rb = wc * 32 + n * 16 + lr;
    #pragma unroll
    for (int ks = 0; ks < 2; ++ks)
      boff[n][ks] = rb * 64 + ((ks * 32 + lg * 8) ^ ((rb & 7) << 3));
  }

  f32x4 acc[2][2][4][2];
  #pragma unroll
  for (int mh = 0; mh < 2; ++mh)
    #pragma unroll
    for (int nh = 0; nh < 2; ++nh)
      #pragma unroll
      for (int m = 0; m < 4; ++m)
        #pragma unroll
        for (int n = 0; n < 2; ++n)
          acc[mh][nh][m][n] = (f32x4){0.f, 0.f, 0.f, 0.f};

  short8 a0[4][2], a1[4][2], b[2][2];

  const int nt = D >> 6;
  PD_STAGE(sm, 0, 0); PD_STAGE(sm, 1, 0); PD_STAGE(sm, 2, 0); PD_STAGE(sm, 3, 0);
  VMWAIT("vmcnt(0)");
  SBAR();

  for (int it = 0; it < nt; ++it){
    const unsigned short* db = sm + (size_t)(it & 1) * 32768;
    unsigned short* sb = sm + (size_t)((it & 1) ^ 1) * 32768;
    const bool hn = (it + 1 < nt);
    const int ktn = (it + 1) << 6;
    // phase 0: consume (A0,B0); stage A0'
    RD_A(a0, db);
    RD_B(db + 2 * 8192);
    if (hn){ PD_STAGE(sb, 0, ktn); VMWAIT("vmcnt(4)"); } else { VMWAIT("vmcnt(4)"); }
    SBAR();
    LGKM0();
    MFMA16(a0, 0, 0);
    // phase 1: consume (A1,B0); stage B0'
    RD_A(a1, db + 8192);
    if (hn){ PD_STAGE(sb, 2, ktn); VMWAIT("vmcnt(4)"); } else { VMWAIT("vmcnt(2)"); }
    SBAR();
    LGKM0();
    MFMA16(a1, 1, 0);
    // phase 2: consume (A1,B1); stage A1'
    RD_B(db + 3 * 8192);
    if (hn){ PD_STAGE(sb, 1, ktn); VMWAIT("vmcnt(4)"); } else { VMWAIT("vmcnt(0)"); }
    SBAR();
    LGKM0();
    MFMA16(a1, 1, 1);
    // phase 3: consume (A0,B1) from registers; stage B1'
    if (hn){ PD_STAGE(sb, 3, ktn); VMWAIT("vmcnt(4)"); }
    SBAR();
    MFMA16(a0, 0, 1);
  }

  // epilogue
  const bool docol = (!pdc) && (bx != by);
  int jl[2][2]; float xj[2][2], hpj[2][2];
  #pragma unroll
  for (int nh = 0; nh < 2; ++nh)
    #pragma unroll
    for (int n = 0; n < 2; ++n){
      int j = j0 + nh * 128 + wc * 32 + n * 16 + lr;
      jl[nh][n] = pdc ? j : labels[j];
      xj[nh][n] = cxv[j];
      hpj[nh][n] = docol ? hpos[j] : 0.f;
    }
  float cmn[2][2], cmx[2][2]; int cfl[2][2];
  #pragma unroll
  for (int nh = 0; nh < 2; ++nh)
    #pragma unroll
    for (int n = 0; n < 2; ++n){ cmn[nh][n] = BIGF; cmx[nh][n] = 0.f; cfl[nh][n] = 0; }

  #pragma unroll
  for (int mh = 0; mh < 2; ++mh)
    #pragma unroll
    for (int m = 0; m < 4; ++m)
      #pragma unroll
      for (int r = 0; r < 4; ++r){
        int i = i0 + mh * 128 + wr * 64 + m * 16 + lg * 4 + r;
        int li = labels[i];
        float xi = exx[i];
        float hpi = hpos[i];
        float mn = BIGF, mx = 0.f; int fl = 0;
        #pragma unroll
        for (int nh = 0; nh < 2; ++nh)
          #pragma unroll
          for (int n = 0; n < 2; ++n){
            float d2 = xi + xj[nh][n] - 2.f * acc[mh][nh][m][n][r];
            float d  = sqrtf(fmaxf(d2, EPSC));
            bool an = (li != jl[nh][n]);
            bool g  = an && (d > hpi);
            mn = fminf(mn, g ? d : BIGF);
            mx = fmaxf(mx, an ? d : 0.f);
            fl |= (g ? 1 : 0) | (an ? 2 : 0);
            if (docol){
              bool gc = an && (d > hpj[nh][n]);
              cmn[nh][n] = fminf(cmn[nh][n], gc ? d : BIGF);
              cmx[nh][n] = fmaxf(cmx[nh][n], an ? d : 0.f);
              cfl[nh][n] |= (gc ? 1 : 0) | (an ? 2 : 0);
            }
          }
        #pragma unroll
        for (int s = 1; s < 16; s <<= 1){
          mn = fminf(mn, __shfl_xor(mn, s));
          mx = fmaxf(mx, __shfl_xor(mx, s));
          fl |= __shfl_xor(fl, s);
        }
        if (lr == 0){
          atomicMin(&mnv[i], __float_as_uint(mn));
          atomicMax(&mxv[i], __float_as_uint(mx));
          if (fl) atomicOr(&flv[i], (unsigned)fl);
        }
      }
  if (docol){
    #pragma unroll
    for (int nh = 0; nh < 2; ++nh)
      #pragma unroll
      for (int n = 0; n < 2; ++n){
        float mn = cmn[nh][n], mx = cmx[nh][n]; int fl = cfl[nh][n];
        #pragma unroll
        for (int s = 16; s < 64; s <<= 1){
          mn = fminf(mn, __shfl_xor(mn, s));
          mx = fmaxf(mx, __shfl_xor(mx, s));
          fl |= __shfl_xor(fl, s);
        }
        if (lg == 0){
          int j = j0 + nh * 128 + wc * 32 + n * 16 + lr;
          atomicMin(&mn0[j], __float_as_uint(mn));
          atomicMax(&mx0[j], __float_as_uint(mx));
          if (fl) atomicOr(&fl0[j], (unsigned)fl);
        }
      }
  }
}

// ---------------- combine + loss ----------------
__global__ __launch_bounds__(1024) void k_final(const float* __restrict__ hpos,
    const unsigned* __restrict__ mn0, const unsigned* __restrict__ mx0,
    const unsigned* __restrict__ fl0, const unsigned* __restrict__ mn1,
    const unsigned* __restrict__ mx1, const unsigned* __restrict__ fl1,
    const float* __restrict__ margin, float* __restrict__ out, int B){
  __shared__ float red[16];
  float part = 0.f;
  float mar = margin[0];
  for (int i = threadIdx.x; i < B; i += blockDim.x){
    float h_out = fminf(__uint_as_float(mn0[i]), __uint_as_float(mn1[i]));
    unsigned f0 = fl0[i], f1 = fl1[i];
    float ni  = (!(f0 & 1u)) ? __uint_as_float(mx0[i]) : ((f0 & 2u) ? BIGF : 0.f);
    float nic = (!(f1 & 1u)) ? __uint_as_float(mx1[i]) : ((f1 & 2u) ? BIGF : 0.f);
    float h_in = fmaxf(ni, nic);
    float hneg = fminf(h_out, h_in);
    float t = hpos[i] - hneg + mar;
    part += fmaxf(t, 0.f);
  }
  #pragma unroll
  for (int s = 32; s; s >>= 1) part += __shfl_xor(part, s);
  if ((threadIdx.x & 63) == 0) red[threadIdx.x >> 6] = part;
  __syncthreads();
  if (threadIdx.x == 0){
    float tot = 0.f;
    int nw = blockDim.x >> 6;
    for (int k = 0; k < nw; ++k) tot += red[k];
    out[0] = tot / (float)B;
  }
}

extern "C" void kernel_launch(void* const* d_in, const int* in_sizes, int n_in,
                              void* d_out, int out_size, void* d_ws, size_t ws_size,
                              hipStream_t stream){
  const float* emb    = (const float*)d_in[0];
  const int*   labels = (const int*)d_in[1];
  const float* cval   = (const float*)d_in[2];
  const float* ccnt   = (const float*)d_in[3];
  const float* margin = (const float*)d_in[4];
  float* out = (float*)d_out;

  int B = in_sizes[1];
  int D = in_sizes[0] / B;
  int C = in_sizes[2] / D;
  const int MMAX = 64;

  char* ws = (char*)d_ws;
  size_t off = 0;
  auto alloc = [&](size_t bytes)->char*{
    char* p = ws + off;
    off = (off + bytes + 255) & ~(size_t)255;
    return p;
  };
  unsigned short* enb = (unsigned short*)alloc((size_t)B * D * 2);
  unsigned short* cnb = (unsigned short*)alloc((size_t)C * D * 2);
  float* exx  = (float*)alloc((size_t)B * 4);
  float* cxx  = (float*)alloc((size_t)C * 4);
  float* hpos = (float*)alloc((size_t)B * 4);
  unsigned* mn0 = (unsigned*)alloc((size_t)B * 4);
  unsigned* mx0 = (unsigned*)alloc((size_t)B * 4);
  unsigned* fl0 = (unsigned*)alloc((size_t)B * 4);
  unsigned* mn1 = (unsigned*)alloc((size_t)B * 4);
  unsigned* mx1 = (unsigned*)alloc((size_t)B * 4);
  unsigned* fl1 = (unsigned*)alloc((size_t)B * 4);
  int* cnt     = (int*)alloc((size_t)C * 4);
  int* members = (int*)alloc((size_t)C * MMAX * 4);
  (void)ws_size; (void)n_in; (void)out_size;

  hipFuncSetAttribute((const void*)k_pd_all,
                      hipFuncAttributeMaxDynamicSharedMemorySize, 131072);

  int nbNorm = B / 4, nbCent = C / 4;
  int R = D >> 9;
  if (R == 4){
    k_prep<4><<<nbNorm + nbCent, 256, 0, stream>>>(emb, cval, ccnt, labels, cnt, members,
                                                   enb, cnb, exx, cxx,
                                                   mn0, mx0, fl0, mn1, mx1, fl1,
                                                   B, D, MMAX, nbNorm);
  } else if (R == 2){
    k_prep<2><<<nbNorm + nbCent, 256, 0, stream>>>(emb, cval, ccnt, labels, cnt, members,
                                                   enb, cnb, exx, cxx,
                                                   mn0, mx0, fl0, mn1, mx1, fl1,
                                                   B, D, MMAX, nbNorm);
  } else {
    k_prep<1><<<nbNorm + nbCent, 256, 0, stream>>>(emb, cval, ccnt, labels, cnt, members,
                                                   enb, cnb, exx, cxx,
                                                   mn0, mx0, fl0, mn1, mx1, fl1,
                                                   B, D, MMAX, nbNorm);
  }

  switch (R){
    case 1: k_hpos<1><<<B/4, 256, 0, stream>>>(enb, cnb, exx, cxx, labels, cnt, members, hpos, D, MMAX); break;
    case 2: k_hpos<2><<<B/4, 256, 0, stream>>>(enb, cnb, exx, cxx, labels, cnt, members, hpos, D, MMAX); break;
    default: k_hpos<4><<<B/4, 256, 0, stream>>>(enb, cnb, exx, cxx, labels, cnt, members, hpos, D, MMAX); break;
  }

  int nby = B / 256, nCx = C / 256;
  int nTri = nby * (nby + 1) / 2;
  k_pd_all<<<nTri + nby * nCx, 512, 131072, stream>>>(
      enb, cnb, exx, cxx, labels, hpos,
      mn0, mx0, fl0, mn1, mx1, fl1, D, nTri, nby, nCx);
  k_final<<<1, 1024, 0, stream>>>(hpos, mn0, mx0, fl0, mn1, mx1, fl1, margin, out, B);
}